// Round 2
// baseline (1590.762 us; speedup 1.0000x reference)
//
#include <hip/hip_runtime.h>
#include <math.h>

// Problem constants
#define BATCH 4
#define CIN 512
#define MID 512
#define HH 50
#define WW 50
#define HWPIX 2500            // 50*50
#define NPIX 10000            // BATCH*HWPIX
#define NANCH 22500           // HWPIX*9
#define NPRE 1200
#define NPOST 300
#define LOCS_OFF 0
#define SCORES_OFF 360000     // BATCH*NANCH*4
#define ROIS_OFF 540000       // + BATCH*NANCH*2

// ---------------------------------------------------------------------------
// K1: transpose W1 (OIHW, [m][c][ky][kx]) -> W1T [kk][c][m]
// ---------------------------------------------------------------------------
__global__ void wt_kernel(const float* __restrict__ W1, float* __restrict__ w1t) {
    int g = blockIdx.x * 256 + threadIdx.x;           // 9*512*512 total
    if (g >= 9 * 512 * 512) return;
    int kk = g / (512 * 512);
    int r  = g % (512 * 512);
    int c  = r / 512;
    int m  = r % 512;
    w1t[g] = W1[(size_t)m * 4608 + c * 9 + kk];
}

// ---------------------------------------------------------------------------
// K2: 3x3 conv (implicit im2col GEMM) + bias + relu -> h [pixel][m] (NHWC)
// M = NPIX pixels, N = 512, K = 9*512. Tile 64x64x16, 4x4 micro.
// ---------------------------------------------------------------------------
__global__ __launch_bounds__(256) void conv3x3_kernel(
    const float* __restrict__ x, const float* __restrict__ w1t,
    const float* __restrict__ b1, float* __restrict__ h) {
    __shared__ float As[16][64];
    __shared__ float Bs[16][64];

    const int t  = threadIdx.x;
    const int tx = t & 15;        // n micro index
    const int ty = t >> 4;        // m (pixel) micro index
    const int m0 = blockIdx.x * 64;   // pixel base
    const int n0 = blockIdx.y * 64;   // out-channel base

    const int pix = t & 63;       // load lane: pixel within tile
    const int cl0 = t >> 6;       // 0..3

    const int P  = m0 + pix;
    const bool vp = (P < NPIX);
    const int b  = P / HWPIX;
    const int pl = P % HWPIX;
    const int yy = pl / WW;
    const int xx = pl % WW;

    float acc[4][4] = {};

    for (int kk = 0; kk < 9; ++kk) {
        const int ky = kk / 3 - 1, kx = kk % 3 - 1;
        const int y2 = yy + ky, x2 = xx + kx;
        const bool v = vp && ((unsigned)y2 < (unsigned)HH) && ((unsigned)x2 < (unsigned)WW);
        const float* xbase = x + (size_t)b * CIN * HWPIX + y2 * WW + x2; // + c*HWPIX
        const float* wbase = w1t + (size_t)kk * 512 * 512 + n0;          // + c*512 + m

        for (int ct = 0; ct < 512 / 16; ++ct) {
            __syncthreads();
            #pragma unroll
            for (int r = 0; r < 4; ++r) {
                const int cl = cl0 + r * 4;
                const int c  = ct * 16 + cl;
                As[cl][pix] = v ? xbase[(size_t)c * HWPIX] : 0.f;
                Bs[cl][pix] = wbase[c * 512 + pix];
            }
            __syncthreads();
            #pragma unroll
            for (int k = 0; k < 16; ++k) {
                const float4 a4 = *reinterpret_cast<const float4*>(&As[k][ty * 4]);
                const float4 b4 = *reinterpret_cast<const float4*>(&Bs[k][tx * 4]);
                const float av[4] = {a4.x, a4.y, a4.z, a4.w};
                const float bv[4] = {b4.x, b4.y, b4.z, b4.w};
                #pragma unroll
                for (int i = 0; i < 4; ++i)
                    #pragma unroll
                    for (int j = 0; j < 4; ++j)
                        acc[i][j] = fmaf(av[i], bv[j], acc[i][j]);
            }
        }
    }

    #pragma unroll
    for (int i = 0; i < 4; ++i) {
        const int Pp = m0 + ty * 4 + i;
        if (Pp >= NPIX) continue;
        const int m = n0 + tx * 4;
        float4 o;
        o.x = fmaxf(acc[i][0] + b1[m + 0], 0.f);
        o.y = fmaxf(acc[i][1] + b1[m + 1], 0.f);
        o.z = fmaxf(acc[i][2] + b1[m + 2], 0.f);
        o.w = fmaxf(acc[i][3] + b1[m + 3], 0.f);
        *reinterpret_cast<float4*>(&h[(size_t)Pp * 512 + m]) = o;
    }
}

// ---------------------------------------------------------------------------
// K3: 1x1 heads GEMM (M=NPIX, N=54 [36 loc + 18 score], K=512) + epilogue:
// writes rpn_locs, rpn_scores to d_out, fg (exact softmax form) to ws.
// ---------------------------------------------------------------------------
__global__ __launch_bounds__(256) void heads_kernel(
    const float* __restrict__ h, const float* __restrict__ Wl,
    const float* __restrict__ bl, const float* __restrict__ Wsc,
    const float* __restrict__ bsc, float* __restrict__ out,
    float* __restrict__ fgb) {
    __shared__ float As[16][64];
    __shared__ float Bs[16][64];

    const int t  = threadIdx.x;
    const int tx = t & 15;
    const int ty = t >> 4;
    const int m0 = blockIdx.x * 64;

    // A-load mapping: each thread loads one float4 of channels for one pixel
    const int pixA = t >> 2;            // 0..63
    const int cq   = (t & 3) * 4;       // 0,4,8,12
    const int PA   = m0 + pixA;
    const bool vA  = (PA < NPIX);
    const float* hA = h + (size_t)(vA ? PA : 0) * 512 + cq;

    // B-load mapping
    const int nB  = t & 63;
    const int cl0 = t >> 6;

    float acc[4][4] = {};

    for (int ct = 0; ct < 32; ++ct) {
        __syncthreads();
        float4 av = make_float4(0.f, 0.f, 0.f, 0.f);
        if (vA) av = *reinterpret_cast<const float4*>(&hA[ct * 16]);
        As[cq + 0][pixA] = av.x;
        As[cq + 1][pixA] = av.y;
        As[cq + 2][pixA] = av.z;
        As[cq + 3][pixA] = av.w;
        #pragma unroll
        for (int r = 0; r < 4; ++r) {
            const int cl = cl0 + r * 4;
            const int c  = ct * 16 + cl;
            float wv = 0.f;
            if (nB < 36)      wv = Wl[nB * 512 + c];
            else if (nB < 54) wv = Wsc[(nB - 36) * 512 + c];
            Bs[cl][nB] = wv;
        }
        __syncthreads();
        #pragma unroll
        for (int k = 0; k < 16; ++k) {
            const float4 a4 = *reinterpret_cast<const float4*>(&As[k][ty * 4]);
            const float4 b4 = *reinterpret_cast<const float4*>(&Bs[k][tx * 4]);
            const float av2[4] = {a4.x, a4.y, a4.z, a4.w};
            const float bv2[4] = {b4.x, b4.y, b4.z, b4.w};
            #pragma unroll
            for (int i = 0; i < 4; ++i)
                #pragma unroll
                for (int j = 0; j < 4; ++j)
                    acc[i][j] = fmaf(av2[i], bv2[j], acc[i][j]);
        }
    }

    #pragma unroll
    for (int i = 0; i < 4; ++i) {
        const int P = m0 + ty * 4 + i;
        if (P >= NPIX) continue;
        const int b  = P / HWPIX;
        const int pl = P % HWPIX;
        const int n  = tx * 4;
        const size_t abase = (size_t)b * NANCH + (size_t)pl * 9;
        if (n < 36) {
            const int a = tx;  // n = 4*tx, k = 0..3
            float4 o;
            o.x = acc[i][0] + bl[n + 0];
            o.y = acc[i][1] + bl[n + 1];
            o.z = acc[i][2] + bl[n + 2];
            o.w = acc[i][3] + bl[n + 3];
            *reinterpret_cast<float4*>(&out[LOCS_OFF + (abase + a) * 4]) = o;
        } else if (n < 54) {
            // ns in {0,4,8,12,16}. ns==16 covers only channels 16,17 (anchor 8):
            // writing a second pair there corrupted the next pixel's anchor 0
            // (cross-wave race on scores + fgb) — that was the round-1 bug.
            const int ns = n - 36;
            float* so = out + SCORES_OFF;
            {
                const float s0 = acc[i][0] + bsc[ns + 0];
                const float s1 = acc[i][1] + bsc[ns + 1];
                const int a0 = ns >> 1;
                so[(abase + a0) * 2 + 0] = s0;
                so[(abase + a0) * 2 + 1] = s1;
                // exact jax.nn.softmax form: subtract max, exp, normalize
                const float mx = fmaxf(s0, s1);
                const float e0 = expf(s0 - mx);
                const float e1 = expf(s1 - mx);
                fgb[abase + a0] = e1 / (e0 + e1);
            }
            if (ns + 3 < 18) {
                const float s0 = acc[i][2] + bsc[ns + 2];
                const float s1 = acc[i][3] + bsc[ns + 3];
                const int a1 = (ns >> 1) + 1;
                so[(abase + a1) * 2 + 0] = s0;
                so[(abase + a1) * 2 + 1] = s1;
                const float mx = fmaxf(s0, s1);
                const float e0 = expf(s0 - mx);
                const float e1 = expf(s1 - mx);
                fgb[abase + a1] = e1 / (e0 + e1);
            }
        }
    }
}

// ---------------------------------------------------------------------------
// K4: per-anchor proposal prep: anchors (exact numpy math), loc2bbox, clip,
// min-size filter, pack sort key (score desc, idx asc).
// ---------------------------------------------------------------------------
__global__ void proposal_prep(const float* __restrict__ out,
                              const float* __restrict__ fgb,
                              float* __restrict__ roi_all,
                              unsigned long long* __restrict__ keys) {
    #pragma clang fp contract(off)
    const int j = blockIdx.x * 256 + threadIdx.x;
    const int b = blockIdx.y;
    if (j >= NANCH) return;

    const int a = j % 9;
    const int p = j / 9;
    const int y = p / WW;
    const int x = p % WW;
    const int ri = a / 3, si = a % 3;
    const double rr[3] = {0.5, 1.0, 2.0};
    const double ss[3] = {8.0, 16.0, 32.0};
    const double hh = 16.0 * ss[si] * sqrt(rr[ri]);
    const double wd = 16.0 * ss[si] * sqrt(1.0 / rr[ri]);
    const float ab0 = (float)(8.0 - hh / 2.0);
    const float ab1 = (float)(8.0 - wd / 2.0);
    const float ab2 = (float)(8.0 + hh / 2.0);
    const float ab3 = (float)(8.0 + wd / 2.0);
    const float sy = (float)(y * 16);
    const float sx = (float)(x * 16);
    const float ay1 = sy + ab0;
    const float ax1 = sx + ab1;
    const float ay2 = sy + ab2;
    const float ax2 = sx + ab3;

    const float h  = ay2 - ay1;
    const float w  = ax2 - ax1;
    const float cy = ay1 + 0.5f * h;
    const float cx = ax1 + 0.5f * w;

    const float* L = out + LOCS_OFF + ((size_t)b * NANCH + j) * 4;
    const float dy = L[0], dx = L[1], dh = L[2], dw = L[3];

    const float ncy = dy * h + cy;
    const float ncx = dx * w + cx;
    const float nh  = expf(dh) * h;
    const float nw  = expf(dw) * w;

    float r0 = ncy - 0.5f * nh;
    float r1 = ncx - 0.5f * nw;
    float r2 = ncy + 0.5f * nh;
    float r3 = ncx + 0.5f * nw;
    r0 = fminf(fmaxf(r0, 0.f), 800.f);
    r1 = fminf(fmaxf(r1, 0.f), 800.f);
    r2 = fminf(fmaxf(r2, 0.f), 800.f);
    r3 = fminf(fmaxf(r3, 0.f), 800.f);

    const float hs  = r2 - r0;
    const float wsz = r3 - r1;
    const float fg  = fgb[(size_t)b * NANCH + j];
    const float s   = (hs >= 16.f && wsz >= 16.f) ? fg : -__builtin_huge_valf();

    float4 ro;
    ro.x = r0; ro.y = r1; ro.z = r2; ro.w = r3;
    *reinterpret_cast<float4*>(&roi_all[((size_t)b * NANCH + j) * 4]) = ro;

    unsigned int bits = __float_as_uint(s);
    unsigned int o = (bits & 0x80000000u) ? ~bits : (bits | 0x80000000u);
    keys[(size_t)b * NANCH + j] =
        ((unsigned long long)o << 32) | (unsigned int)(~(unsigned int)j);
}

// ---------------------------------------------------------------------------
// K5: per-batch exact top-1200: 8-pass radix select for 1200th key, compact,
// bitonic sort (2048, descending) in LDS, gather sorted boxes.
// ---------------------------------------------------------------------------
__global__ __launch_bounds__(1024) void select_sort_kernel(
    const unsigned long long* __restrict__ keys,
    const float* __restrict__ roi_all, float* __restrict__ boxes) {
    const int b   = blockIdx.x;
    const int tid = threadIdx.x;
    const unsigned long long* K = keys + (size_t)b * NANCH;

    __shared__ unsigned int hist[256];
    __shared__ unsigned long long sbuf[2048];
    __shared__ unsigned long long prefix_s;
    __shared__ int rank_s;
    __shared__ int cnt_s;

    if (tid == 0) { prefix_s = 0ULL; rank_s = NPRE; }
    __syncthreads();

    for (int pass = 0; pass < 8; ++pass) {
        for (int i = tid; i < 256; i += 1024) hist[i] = 0;
        __syncthreads();
        const int sh = 56 - 8 * pass;
        const unsigned long long pref = prefix_s;
        for (int i = tid; i < NANCH; i += 1024) {
            const unsigned long long k = K[i];
            const bool match = (pass == 0) || ((k >> (sh + 8)) == pref);
            if (match) atomicAdd(&hist[(unsigned)(k >> sh) & 255u], 1u);
        }
        __syncthreads();
        if (tid == 0) {
            int r = rank_s;
            int d;
            for (d = 255; d > 0; --d) {
                const int c = (int)hist[d];
                if (r <= c) break;
                r -= c;
            }
            rank_s = r;
            prefix_s = (prefix_s << 8) | (unsigned long long)(unsigned)d;
        }
        __syncthreads();
    }

    const unsigned long long kth = prefix_s;
    if (tid == 0) cnt_s = 0;
    __syncthreads();
    for (int i = tid; i < NANCH; i += 1024) {
        const unsigned long long k = K[i];
        if (k >= kth) {
            const int p = atomicAdd(&cnt_s, 1);
            if (p < 2048) sbuf[p] = k;
        }
    }
    __syncthreads();
    const int cnt = cnt_s;
    for (int i = tid; i < 2048; i += 1024)
        if (i >= cnt) sbuf[i] = 0ULL;

    // bitonic sort, descending
    for (int ksz = 2; ksz <= 2048; ksz <<= 1) {
        for (int jj = ksz >> 1; jj > 0; jj >>= 1) {
            __syncthreads();
            for (int i = tid; i < 2048; i += 1024) {
                const int l = i ^ jj;
                if (l > i) {
                    const unsigned long long a = sbuf[i];
                    const unsigned long long c = sbuf[l];
                    const bool asc = (i & ksz) != 0;
                    const bool sw  = asc ? (a > c) : (a < c);
                    if (sw) { sbuf[i] = c; sbuf[l] = a; }
                }
            }
        }
    }
    __syncthreads();

    for (int r = tid; r < NPRE; r += 1024) {
        const unsigned long long k = sbuf[r];
        const unsigned int idx = ~((unsigned int)k);
        const float4 v = *reinterpret_cast<const float4*>(
            &roi_all[((size_t)b * NANCH + idx) * 4]);
        *reinterpret_cast<float4*>(&boxes[((size_t)b * NPRE + r) * 4]) = v;
    }
}

// ---------------------------------------------------------------------------
// K6: 1200x1200 IoU suppression bitmask per batch.
// ---------------------------------------------------------------------------
__global__ __launch_bounds__(1024) void iou_kernel(
    const float* __restrict__ boxes, unsigned long long* __restrict__ mask) {
    #pragma clang fp contract(off)
    const int b = blockIdx.x;
    const int t = threadIdx.x;
    __shared__ float bx[NPRE * 4];
    __shared__ float ar[NPRE];

    for (int i = t; i < NPRE * 4; i += 1024)
        bx[i] = boxes[(size_t)b * NPRE * 4 + i];
    __syncthreads();
    for (int i = t; i < NPRE; i += 1024)
        ar[i] = (bx[i * 4 + 2] - bx[i * 4 + 0]) * (bx[i * 4 + 3] - bx[i * 4 + 1]);
    __syncthreads();

    for (int i = t; i < NPRE; i += 1024) {
        const float y1 = bx[i * 4 + 0], x1 = bx[i * 4 + 1];
        const float y2 = bx[i * 4 + 2], x2 = bx[i * 4 + 3];
        const float ai = ar[i];
        for (int jw = 0; jw < 19; ++jw) {
            unsigned long long bits = 0ULL;
            const int jmax = (jw * 64 + 64 <= NPRE) ? 64 : (NPRE - jw * 64);
            for (int jb = 0; jb < jmax; ++jb) {
                const int j = jw * 64 + jb;
                const float iy = fmaxf(fminf(y2, bx[j * 4 + 2]) - fmaxf(y1, bx[j * 4 + 0]), 0.f);
                const float ix = fmaxf(fminf(x2, bx[j * 4 + 3]) - fmaxf(x1, bx[j * 4 + 1]), 0.f);
                const float inter = iy * ix;
                const float den = ((ai + ar[j]) - inter) + 1e-9f;
                const float iou = inter / den;
                if (iou > 0.7f) bits |= (1ULL << jb);
            }
            mask[((size_t)b * NPRE + i) * 19 + jw] = bits;
        }
    }
}

// ---------------------------------------------------------------------------
// K7: serial greedy NMS scan (single wave, 1-ahead prefetch) + final top-300
// selection with jax top_k fill semantics, write rois.
// ---------------------------------------------------------------------------
__global__ __launch_bounds__(64) void nms_scan_kernel(
    const unsigned long long* __restrict__ mask,
    const float* __restrict__ boxes, float* __restrict__ out_rois) {
    const int b    = blockIdx.x;
    const int lane = threadIdx.x;
    const unsigned long long* M = mask + (size_t)b * NPRE * 19;

    __shared__ unsigned char keepA[NPRE];
    __shared__ int sel[NPOST];

    unsigned long long sup = 0ULL;   // lane w (<19) owns word w
    unsigned long long nxt = (lane < 19) ? M[lane] : 0ULL;
    int nk = 0;

    for (int i = 0; i < NPRE; ++i) {
        const unsigned long long row = nxt;
        if (lane < 19) nxt = (i + 1 < NPRE) ? M[(size_t)(i + 1) * 19 + lane] : 0ULL;
        const unsigned long long supw = __shfl(sup, i >> 6, 64);
        const bool k = ((supw >> (i & 63)) & 1ULL) == 0ULL;
        if (lane == 0) {
            keepA[i] = k ? 1 : 0;
            if (k && nk < NPOST) sel[nk] = i;
        }
        if (k) {
            ++nk;
            if (lane < 19) sup |= row;
        }
    }

    if (lane == 0) {
        int cnt = (nk < NPOST) ? nk : NPOST;
        for (int i = 0; i < NPRE && cnt < NPOST; ++i)
            if (!keepA[i]) sel[cnt++] = i;
    }
    __syncthreads();

    for (int r = lane; r < NPOST; r += 64) {
        const int i = sel[r];
        const float4 v = *reinterpret_cast<const float4*>(
            &boxes[((size_t)b * NPRE + i) * 4]);
        *reinterpret_cast<float4*>(&out_rois[((size_t)b * NPOST + r) * 4]) = v;
    }
}

// ---------------------------------------------------------------------------
extern "C" void kernel_launch(void* const* d_in, const int* in_sizes, int n_in,
                              void* d_out, int out_size, void* d_ws, size_t ws_size,
                              hipStream_t stream) {
    const float* x   = (const float*)d_in[0];
    const float* W1  = (const float*)d_in[1];
    const float* b1  = (const float*)d_in[2];
    const float* Wl  = (const float*)d_in[3];
    const float* bl  = (const float*)d_in[4];
    const float* Wsc = (const float*)d_in[5];
    const float* bsc = (const float*)d_in[6];
    float* out = (float*)d_out;
    float* ws  = (float*)d_ws;

    // Workspace layout (floats; all 16B-aligned)
    float* w1t     = ws;                              // 9*512*512      = 2359296
    float* h       = w1t + 2359296;                   // NPIX*512       = 5120000
    float* fgb     = h + 5120000;                     // BATCH*NANCH    = 90000
    float* roi_all = fgb + 90000;                     // BATCH*NANCH*4  = 360000
    unsigned long long* keys = (unsigned long long*)(roi_all + 360000); // 90000 u64
    float* boxes   = (float*)(keys + 90000);          // BATCH*NPRE*4   = 19200
    unsigned long long* mask = (unsigned long long*)(boxes + 19200);    // BATCH*NPRE*19 u64

    hipLaunchKernelGGL(wt_kernel, dim3((9 * 512 * 512 + 255) / 256), dim3(256), 0, stream,
                       W1, w1t);
    hipLaunchKernelGGL(conv3x3_kernel, dim3((NPIX + 63) / 64, 512 / 64), dim3(256), 0, stream,
                       x, w1t, b1, h);
    hipLaunchKernelGGL(heads_kernel, dim3((NPIX + 63) / 64), dim3(256), 0, stream,
                       h, Wl, bl, Wsc, bsc, out, fgb);
    hipLaunchKernelGGL(proposal_prep, dim3((NANCH + 255) / 256, BATCH), dim3(256), 0, stream,
                       out, fgb, roi_all, keys);
    hipLaunchKernelGGL(select_sort_kernel, dim3(BATCH), dim3(1024), 0, stream,
                       keys, roi_all, boxes);
    hipLaunchKernelGGL(iou_kernel, dim3(BATCH), dim3(1024), 0, stream,
                       boxes, mask);
    hipLaunchKernelGGL(nms_scan_kernel, dim3(BATCH), dim3(64), 0, stream,
                       mask, boxes, out + ROIS_OFF);
}